// Round 1
// baseline (2183.750 us; speedup 1.0000x reference)
//
#include <hip/hip_runtime.h>
#include <hip/hip_bf16.h>

#define N_ROWS 262144
#define IN_DIM 64
#define HID 256
#define EMB 128
#define OUT_DIM 64
#define NSEG 1024
#define LDS_S 264   // 256 + 8 halves pad: 528B row stride = 33*16B (keeps 16B align, breaks bank aliasing)

typedef _Float16 h16;
typedef _Float16 h16x8 __attribute__((ext_vector_type(8)));
typedef float f32x4 __attribute__((ext_vector_type(4)));

// ---------------- prep kernels ----------------

__global__ void k_max(const int* __restrict__ aisle, int* __restrict__ maxA) {
    int v = 0;
    for (int i = blockIdx.x * blockDim.x + threadIdx.x; i < N_ROWS; i += gridDim.x * blockDim.x)
        v = max(v, aisle[i]);
#pragma unroll
    for (int off = 32; off > 0; off >>= 1) v = max(v, __shfl_down(v, off));
    __shared__ int red[4];
    if ((threadIdx.x & 63) == 0) red[threadIdx.x >> 6] = v;
    __syncthreads();
    if (threadIdx.x == 0) {
        int m = red[0];
        for (int i = 1; i < 4; ++i) m = max(m, red[i]);
        atomicMax(maxA, m);
    }
}

// transpose + fp32->fp16 all six weight matrices into [Nout][K] layout
__global__ void k_prep_weights(const float* __restrict__ W1, const float* __restrict__ W2,
                               const float* __restrict__ W3, const float* __restrict__ A1f,
                               const float* __restrict__ A2f, const float* __restrict__ A3f,
                               h16* __restrict__ W1t, h16* __restrict__ W2t, h16* __restrict__ W3t,
                               h16* __restrict__ A1t, h16* __restrict__ A2t, h16* __restrict__ A3t) {
    int idx = blockIdx.x * 256 + threadIdx.x;      // total 262144 threads
    if (idx < 16384)       { int o = idx;          int n = o >> 6, k = o & 63;  W1t[o] = (h16)W1[k * 256 + n]; }
    else if (idx < 81920)  { int o = idx - 16384;  int n = o >> 8, k = o & 255; W2t[o] = (h16)W2[k * 256 + n]; }
    else if (idx < 114688) { int o = idx - 81920;  int n = o >> 8, k = o & 255; W3t[o] = (h16)W3[k * 128 + n]; }
    else if (idx < 180224) { int o = idx - 114688; int n = o >> 8, k = o & 255; A1t[o] = (h16)A1f[k * 256 + n]; }
    else if (idx < 245760) { int o = idx - 180224; int n = o >> 8, k = o & 255; A2t[o] = (h16)A2f[k * 256 + n]; }
    else                   { int o = idx - 245760; int n = o >> 8, k = o & 255; A3t[o] = (h16)A3f[k * 64  + n]; }
}

__global__ void k_means(const float* __restrict__ sums, const float* __restrict__ counts,
                        h16* __restrict__ means) {
    int i = blockIdx.x * 256 + threadIdx.x;        // 131072 total
    int s = i >> 7;
    float c = counts[s];
    means[i] = (h16)(sums[i] / fmaxf(c, 1.0f));
}

// ---------------- fused MLP layer (in-place LDS) ----------------
// S holds [64 rows][K cols] fp16 activations (stride LDS_S). Computes
// lrelu?(S @ Wt^T + bias) into S[64][NOUT]. Wt is [NOUT][K] fp16.
// MFMA 16x16x32_f16 layouts (learn_hip verified):
//   A: m=lane&15, k=(lane>>4)*8+j   B: n=lane&15, k=(lane>>4)*8+j
//   C: col=lane&15, row=(lane>>4)*4+r
template <int K, int NOUT, bool ACT>
__device__ __forceinline__ void mlp_layer(const h16* __restrict__ Wt,
                                          const float* __restrict__ bias,
                                          h16* S, int lane, int wave) {
    constexpr int NW = NOUT / 4;   // cols per wave
    constexpr int NT = NW / 16;    // n-tiles per wave
    constexpr int KT = K / 32;     // k-steps
    const int l15 = lane & 15, l4 = lane >> 4;
    f32x4 acc[4][NT];
#pragma unroll
    for (int mt = 0; mt < 4; ++mt)
#pragma unroll
        for (int nt = 0; nt < NT; ++nt)
#pragma unroll
            for (int j = 0; j < 4; ++j) acc[mt][nt][j] = 0.f;

#pragma unroll
    for (int kt = 0; kt < KT; ++kt) {
        h16x8 a[4];
#pragma unroll
        for (int mt = 0; mt < 4; ++mt)
            a[mt] = *(const h16x8*)&S[(mt * 16 + l15) * LDS_S + kt * 32 + l4 * 8];
#pragma unroll
        for (int nt = 0; nt < NT; ++nt) {
            const int n = wave * NW + nt * 16 + l15;
            h16x8 b = *(const h16x8*)&Wt[n * K + kt * 32 + l4 * 8];
#pragma unroll
            for (int mt = 0; mt < 4; ++mt)
                acc[mt][nt] = __builtin_amdgcn_mfma_f32_16x16x32_f16(a[mt], b, acc[mt][nt], 0, 0, 0);
        }
    }
    __syncthreads();   // all reads of S done before in-place overwrite
#pragma unroll
    for (int nt = 0; nt < NT; ++nt) {
        const int col = wave * NW + nt * 16 + l15;
        const float bv = bias[col];
#pragma unroll
        for (int mt = 0; mt < 4; ++mt)
#pragma unroll
            for (int r = 0; r < 4; ++r) {
                float v = acc[mt][nt][r] + bv;
                if (ACT) v = (v > 0.f) ? v : 0.01f * v;
                S[(mt * 16 + l4 * 4 + r) * LDS_S + col] = (h16)v;
            }
    }
    __syncthreads();   // new acts visible
}

// ---------------- phase 1: x -> h, scatter segment sums ----------------
__global__ __launch_bounds__(256) void k1(const float* __restrict__ x,
                                          const int* __restrict__ aisle,
                                          const int* __restrict__ batch,
                                          const h16* __restrict__ W1t, const float* __restrict__ b1,
                                          const h16* __restrict__ W2t, const float* __restrict__ b2,
                                          const h16* __restrict__ W3t, const float* __restrict__ b3,
                                          h16* __restrict__ hbuf, float* __restrict__ sums,
                                          float* __restrict__ counts, const int* __restrict__ maxA) {
    __shared__ __align__(16) h16 S[64 * LDS_S];
    const int tid = threadIdx.x, lane = tid & 63, wave = tid >> 6;
    const int row0 = blockIdx.x * 64;

    // load x tile [64][64] fp32 -> fp16 LDS
    for (int i = tid; i < 1024; i += 256) {
        int r = i >> 4, c4 = (i & 15) * 4;
        f32x4 v = *(const f32x4*)&x[(size_t)(row0 + r) * 64 + c4];
        h16* dst = &S[r * LDS_S + c4];
        dst[0] = (h16)v[0]; dst[1] = (h16)v[1]; dst[2] = (h16)v[2]; dst[3] = (h16)v[3];
    }
    __syncthreads();

    mlp_layer<64, 256, true>(W1t, b1, S, lane, wave);
    mlp_layer<256, 256, true>(W2t, b2, S, lane, wave);
    mlp_layer<256, 128, false>(W3t, b3, S, lane, wave);

    // store h fp16 [64][128] to global (coalesced 16B chunks)
    for (int i = tid; i < 1024; i += 256) {
        int r = i >> 4, c8 = (i & 15) * 8;
        *(h16x8*)&hbuf[(size_t)(row0 + r) * 128 + c8] = *(const h16x8*)&S[r * LDS_S + c8];
    }

    // scatter: 4 threads per row, 32 cols each
    const int mult = *maxA + 1;
    const int r = tid >> 2, p = tid & 3;
    const int g = row0 + r;
    const int id = aisle[g] + batch[g] * mult;
    float* sdst = &sums[id * 128 + p * 32];
    const h16* src = &S[r * LDS_S + p * 32];
#pragma unroll 8
    for (int c = 0; c < 32; ++c) atomicAdd(&sdst[c], (float)src[c]);
    if (p == 0) atomicAdd(&counts[id], 1.0f);
}

// ---------------- phase 3: concat(h, mean) -> out ----------------
__global__ __launch_bounds__(256) void k3(const h16* __restrict__ hbuf,
                                          const int* __restrict__ aisle,
                                          const int* __restrict__ batch,
                                          const h16* __restrict__ means,
                                          const h16* __restrict__ A1t, const float* __restrict__ c1,
                                          const h16* __restrict__ A2t, const float* __restrict__ c2,
                                          const h16* __restrict__ A3t, const float* __restrict__ c3,
                                          float* __restrict__ out, const int* __restrict__ maxA) {
    __shared__ __align__(16) h16 S[64 * LDS_S];
    const int tid = threadIdx.x, lane = tid & 63, wave = tid >> 6;
    const int row0 = blockIdx.x * 64;
    const int mult = *maxA + 1;

    // h -> cols [0,128)
    for (int i = tid; i < 1024; i += 256) {
        int r = i >> 4, c8 = (i & 15) * 8;
        *(h16x8*)&S[r * LDS_S + c8] = *(const h16x8*)&hbuf[(size_t)(row0 + r) * 128 + c8];
    }
    // gathered means -> cols [128,256)
    {
        const int r = tid >> 2, p = tid & 3;
        const int g = row0 + r;
        const int id = aisle[g] + batch[g] * mult;
        const h16x8* src = (const h16x8*)&means[id * 128 + p * 32];
        h16x8* dst = (h16x8*)&S[r * LDS_S + 128 + p * 32];
        dst[0] = src[0]; dst[1] = src[1]; dst[2] = src[2]; dst[3] = src[3];
    }
    __syncthreads();

    mlp_layer<256, 256, true>(A1t, c1, S, lane, wave);
    mlp_layer<256, 256, true>(A2t, c2, S, lane, wave);

    // final layer: K=256 -> 64 cols, write fp32 directly to global
    {
        const int l15 = lane & 15, l4 = lane >> 4;
        f32x4 acc[4];
#pragma unroll
        for (int mt = 0; mt < 4; ++mt)
#pragma unroll
            for (int j = 0; j < 4; ++j) acc[mt][j] = 0.f;
#pragma unroll
        for (int kt = 0; kt < 8; ++kt) {
            h16x8 b = *(const h16x8*)&A3t[(wave * 16 + l15) * 256 + kt * 32 + l4 * 8];
#pragma unroll
            for (int mt = 0; mt < 4; ++mt) {
                h16x8 a = *(const h16x8*)&S[(mt * 16 + l15) * LDS_S + kt * 32 + l4 * 8];
                acc[mt] = __builtin_amdgcn_mfma_f32_16x16x32_f16(a, b, acc[mt], 0, 0, 0);
            }
        }
        const int col = wave * 16 + l15;
        const float bv = c3[col];
#pragma unroll
        for (int mt = 0; mt < 4; ++mt)
#pragma unroll
            for (int r = 0; r < 4; ++r) {
                int row = row0 + mt * 16 + l4 * 4 + r;
                out[(size_t)row * 64 + col] = acc[mt][r] + bv;
            }
    }
}

// ---------------- host launch ----------------
extern "C" void kernel_launch(void* const* d_in, const int* in_sizes, int n_in,
                              void* d_out, int out_size, void* d_ws, size_t ws_size,
                              hipStream_t stream) {
    const float* x     = (const float*)d_in[0];
    const int*   aisle = (const int*)d_in[1];
    const int*   batch = (const int*)d_in[2];
    const float* W1 = (const float*)d_in[3];  const float* b1 = (const float*)d_in[4];
    const float* W2 = (const float*)d_in[5];  const float* b2 = (const float*)d_in[6];
    const float* W3 = (const float*)d_in[7];  const float* b3 = (const float*)d_in[8];
    const float* A1 = (const float*)d_in[9];  const float* c1 = (const float*)d_in[10];
    const float* A2 = (const float*)d_in[11]; const float* c2 = (const float*)d_in[12];
    const float* A3 = (const float*)d_in[13]; const float* c3 = (const float*)d_in[14];
    float* out = (float*)d_out;

    char* w = (char*)d_ws;
    size_t off = 0;
    h16*   hbuf   = (h16*)(w + off);   off += (size_t)N_ROWS * 128 * sizeof(h16);   // 64 MB
    float* sums   = (float*)(w + off); size_t sums_off = off; off += NSEG * 128 * sizeof(float);
    float* counts = (float*)(w + off); off += NSEG * sizeof(float);
    size_t zero_bytes = off - sums_off;
    h16*   means  = (h16*)(w + off);   off += NSEG * 128 * sizeof(h16);
    h16*   W1t    = (h16*)(w + off);   off += 16384 * sizeof(h16);
    h16*   W2t    = (h16*)(w + off);   off += 65536 * sizeof(h16);
    h16*   W3t    = (h16*)(w + off);   off += 32768 * sizeof(h16);
    h16*   A1t    = (h16*)(w + off);   off += 65536 * sizeof(h16);
    h16*   A2t    = (h16*)(w + off);   off += 65536 * sizeof(h16);
    h16*   A3t    = (h16*)(w + off);   off += 16384 * sizeof(h16);
    int*   maxA   = (int*)(w + off);   off += 256;

    hipMemsetAsync(w + sums_off, 0, zero_bytes, stream);
    hipMemsetAsync(maxA, 0, sizeof(int), stream);

    k_max<<<256, 256, 0, stream>>>(aisle, maxA);
    k_prep_weights<<<1024, 256, 0, stream>>>(W1, W2, W3, A1, A2, A3, W1t, W2t, W3t, A1t, A2t, A3t);
    k1<<<N_ROWS / 64, 256, 0, stream>>>(x, aisle, batch, W1t, b1, W2t, b2, W3t, b3,
                                        hbuf, sums, counts, maxA);
    k_means<<<512, 256, 0, stream>>>(sums, counts, means);
    k3<<<N_ROWS / 64, 256, 0, stream>>>(hbuf, aisle, batch, means, A1t, c1, A2t, c2, A3t, c3,
                                        out, maxA);
}

// Round 2
// 638.656 us; speedup vs baseline: 3.4193x; 3.4193x over previous
//
#include <hip/hip_runtime.h>
#include <hip/hip_bf16.h>

#define N_ROWS 262144
#define IN_DIM 64
#define HID 256
#define EMB 128
#define OUT_DIM 64
#define NSEG 1024
#define LDS_S 264   // 256 + 8 halves pad: 528B row stride = 33*16B (keeps 16B align, breaks bank aliasing)
#define CHUNK 1024  // rows per k_scatter block

typedef _Float16 h16;
typedef _Float16 h16x8 __attribute__((ext_vector_type(8)));
typedef float f32x4 __attribute__((ext_vector_type(4)));

// ---------------- prep kernels ----------------

__global__ void k_max(const int* __restrict__ aisle, int* __restrict__ maxA) {
    int v = 0;
    for (int i = blockIdx.x * blockDim.x + threadIdx.x; i < N_ROWS; i += gridDim.x * blockDim.x)
        v = max(v, aisle[i]);
#pragma unroll
    for (int off = 32; off > 0; off >>= 1) v = max(v, __shfl_down(v, off));
    __shared__ int red[4];
    if ((threadIdx.x & 63) == 0) red[threadIdx.x >> 6] = v;
    __syncthreads();
    if (threadIdx.x == 0) {
        int m = red[0];
        for (int i = 1; i < 4; ++i) m = max(m, red[i]);
        atomicMax(maxA, m);
    }
}

// transpose + fp32->fp16 all six weight matrices into [Nout][K] layout
__global__ void k_prep_weights(const float* __restrict__ W1, const float* __restrict__ W2,
                               const float* __restrict__ W3, const float* __restrict__ A1f,
                               const float* __restrict__ A2f, const float* __restrict__ A3f,
                               h16* __restrict__ W1t, h16* __restrict__ W2t, h16* __restrict__ W3t,
                               h16* __restrict__ A1t, h16* __restrict__ A2t, h16* __restrict__ A3t) {
    int idx = blockIdx.x * 256 + threadIdx.x;      // total 262144 threads
    if (idx < 16384)       { int o = idx;          int n = o >> 6, k = o & 63;  W1t[o] = (h16)W1[k * 256 + n]; }
    else if (idx < 81920)  { int o = idx - 16384;  int n = o >> 8, k = o & 255; W2t[o] = (h16)W2[k * 256 + n]; }
    else if (idx < 114688) { int o = idx - 81920;  int n = o >> 8, k = o & 255; W3t[o] = (h16)W3[k * 128 + n]; }
    else if (idx < 180224) { int o = idx - 114688; int n = o >> 8, k = o & 255; A1t[o] = (h16)A1f[k * 256 + n]; }
    else if (idx < 245760) { int o = idx - 180224; int n = o >> 8, k = o & 255; A2t[o] = (h16)A2f[k * 256 + n]; }
    else                   { int o = idx - 245760; int n = o >> 8, k = o & 255; A3t[o] = (h16)A3f[k * 64  + n]; }
}

__global__ void k_means(const float* __restrict__ sums, const float* __restrict__ counts,
                        h16* __restrict__ means) {
    int i = blockIdx.x * 256 + threadIdx.x;        // 131072 total
    int s = i >> 7;
    float c = counts[s];
    means[i] = (h16)(sums[i] / fmaxf(c, 1.0f));
}

// ---------------- fused MLP layer (in-place LDS) ----------------
// S holds [64 rows][K cols] fp16 activations (stride LDS_S). Computes
// lrelu?(S @ Wt^T + bias) into S[64][NOUT]. Wt is [NOUT][K] fp16.
// MFMA 16x16x32_f16 layouts (learn_hip verified):
//   A: m=lane&15, k=(lane>>4)*8+j   B: n=lane&15, k=(lane>>4)*8+j
//   C: col=lane&15, row=(lane>>4)*4+r
template <int K, int NOUT, bool ACT>
__device__ __forceinline__ void mlp_layer(const h16* __restrict__ Wt,
                                          const float* __restrict__ bias,
                                          h16* S, int lane, int wave) {
    constexpr int NW = NOUT / 4;   // cols per wave
    constexpr int NT = NW / 16;    // n-tiles per wave
    constexpr int KT = K / 32;     // k-steps
    const int l15 = lane & 15, l4 = lane >> 4;
    f32x4 acc[4][NT];
#pragma unroll
    for (int mt = 0; mt < 4; ++mt)
#pragma unroll
        for (int nt = 0; nt < NT; ++nt)
#pragma unroll
            for (int j = 0; j < 4; ++j) acc[mt][nt][j] = 0.f;

#pragma unroll
    for (int kt = 0; kt < KT; ++kt) {
        h16x8 a[4];
#pragma unroll
        for (int mt = 0; mt < 4; ++mt)
            a[mt] = *(const h16x8*)&S[(mt * 16 + l15) * LDS_S + kt * 32 + l4 * 8];
#pragma unroll
        for (int nt = 0; nt < NT; ++nt) {
            const int n = wave * NW + nt * 16 + l15;
            h16x8 b = *(const h16x8*)&Wt[n * K + kt * 32 + l4 * 8];
#pragma unroll
            for (int mt = 0; mt < 4; ++mt)
                acc[mt][nt] = __builtin_amdgcn_mfma_f32_16x16x32_f16(a[mt], b, acc[mt][nt], 0, 0, 0);
        }
    }
    __syncthreads();   // all reads of S done before in-place overwrite
#pragma unroll
    for (int nt = 0; nt < NT; ++nt) {
        const int col = wave * NW + nt * 16 + l15;
        const float bv = bias[col];
#pragma unroll
        for (int mt = 0; mt < 4; ++mt)
#pragma unroll
            for (int r = 0; r < 4; ++r) {
                float v = acc[mt][nt][r] + bv;
                if (ACT) v = (v > 0.f) ? v : 0.01f * v;
                S[(mt * 16 + l4 * 4 + r) * LDS_S + col] = (h16)v;
            }
    }
    __syncthreads();   // new acts visible
}

// ---------------- phase 1: x -> h (no scatter) ----------------
__global__ __launch_bounds__(256) void k1(const float* __restrict__ x,
                                          const h16* __restrict__ W1t, const float* __restrict__ b1,
                                          const h16* __restrict__ W2t, const float* __restrict__ b2,
                                          const h16* __restrict__ W3t, const float* __restrict__ b3,
                                          h16* __restrict__ hbuf) {
    __shared__ __align__(16) h16 S[64 * LDS_S];
    const int tid = threadIdx.x, lane = tid & 63, wave = tid >> 6;
    const int row0 = blockIdx.x * 64;

    // load x tile [64][64] fp32 -> fp16 LDS
    for (int i = tid; i < 1024; i += 256) {
        int r = i >> 4, c4 = (i & 15) * 4;
        f32x4 v = *(const f32x4*)&x[(size_t)(row0 + r) * 64 + c4];
        h16* dst = &S[r * LDS_S + c4];
        dst[0] = (h16)v[0]; dst[1] = (h16)v[1]; dst[2] = (h16)v[2]; dst[3] = (h16)v[3];
    }
    __syncthreads();

    mlp_layer<64, 256, true>(W1t, b1, S, lane, wave);
    mlp_layer<256, 256, true>(W2t, b2, S, lane, wave);
    mlp_layer<256, 128, false>(W3t, b3, S, lane, wave);

    // store h fp16 [64][128] to global (coalesced 16B chunks)
    for (int i = tid; i < 1024; i += 256) {
        int r = i >> 4, c8 = (i & 15) * 8;
        *(h16x8*)&hbuf[(size_t)(row0 + r) * 128 + c8] = *(const h16x8*)&S[r * LDS_S + c8];
    }
}

// ---------------- phase 2: hierarchical segment-sum scatter ----------------
// Each block owns CHUNK contiguous rows. batch is sorted, so a chunk spans a
// contiguous (usually length-1) range of batch values. Accumulate into an LDS
// table keyed by aisle (padded stride 132 to spread the 16 row-walkers across
// banks), flush once per batch value with global atomics.
__global__ __launch_bounds__(256) void k_scatter(const h16* __restrict__ hbuf,
                                                 const int* __restrict__ aisle,
                                                 const int* __restrict__ batch,
                                                 float* __restrict__ sums,
                                                 float* __restrict__ counts,
                                                 const int* __restrict__ maxA) {
    __shared__ float acc[64][132];   // 33792 B, pad 4 so bank = (4a + c) % 32
    __shared__ float cnt[64];
    const int tid = threadIdx.x;
    const int row0 = blockIdx.x * CHUNK;
    const int mult = *maxA + 1;

    for (int i = tid; i < 64 * 132; i += 256) ((float*)acc)[i] = 0.f;
    if (tid < 64) cnt[tid] = 0.f;
    __syncthreads();

    const int bLo = batch[row0], bHi = batch[row0 + CHUNK - 1];
    const int w = tid >> 4;           // 16 row-walkers
    const int c8 = (tid & 15) * 8;    // 8 cols per thread

    for (int bv = bLo; bv <= bHi; ++bv) {
        for (int r = w; r < CHUNK; r += 16) {
            const int g = row0 + r;
            if (batch[g] != bv) continue;
            const int a = aisle[g];
            const h16x8 hv = *(const h16x8*)&hbuf[(size_t)g * 128 + c8];
#pragma unroll
            for (int j = 0; j < 8; ++j) atomicAdd(&acc[a][c8 + j], (float)hv[j]);
            if (c8 == 0) atomicAdd(&cnt[a], 1.0f);
        }
        __syncthreads();
        // flush this batch value's partial sums, re-zero LDS
        for (int i = tid; i < 64 * 128; i += 256) {
            const int a = i >> 7, c = i & 127;
            const float v = acc[a][c];
            if (v != 0.f) {
                atomicAdd(&sums[(size_t)(a + bv * mult) * 128 + c], v);
                acc[a][c] = 0.f;
            }
        }
        if (tid < 64 && cnt[tid] != 0.f) {
            atomicAdd(&counts[tid + bv * mult], cnt[tid]);
            cnt[tid] = 0.f;
        }
        __syncthreads();
    }
}

// ---------------- phase 3: concat(h, mean) -> out ----------------
__global__ __launch_bounds__(256) void k3(const h16* __restrict__ hbuf,
                                          const int* __restrict__ aisle,
                                          const int* __restrict__ batch,
                                          const h16* __restrict__ means,
                                          const h16* __restrict__ A1t, const float* __restrict__ c1,
                                          const h16* __restrict__ A2t, const float* __restrict__ c2,
                                          const h16* __restrict__ A3t, const float* __restrict__ c3,
                                          float* __restrict__ out, const int* __restrict__ maxA) {
    __shared__ __align__(16) h16 S[64 * LDS_S];
    const int tid = threadIdx.x, lane = tid & 63, wave = tid >> 6;
    const int row0 = blockIdx.x * 64;
    const int mult = *maxA + 1;

    // h -> cols [0,128)
    for (int i = tid; i < 1024; i += 256) {
        int r = i >> 4, c8 = (i & 15) * 8;
        *(h16x8*)&S[r * LDS_S + c8] = *(const h16x8*)&hbuf[(size_t)(row0 + r) * 128 + c8];
    }
    // gathered means -> cols [128,256)
    {
        const int r = tid >> 2, p = tid & 3;
        const int g = row0 + r;
        const int id = aisle[g] + batch[g] * mult;
        const h16x8* src = (const h16x8*)&means[id * 128 + p * 32];
        h16x8* dst = (h16x8*)&S[r * LDS_S + 128 + p * 32];
        dst[0] = src[0]; dst[1] = src[1]; dst[2] = src[2]; dst[3] = src[3];
    }
    __syncthreads();

    mlp_layer<256, 256, true>(A1t, c1, S, lane, wave);
    mlp_layer<256, 256, true>(A2t, c2, S, lane, wave);

    // final layer: K=256 -> 64 cols, write fp32 directly to global
    {
        const int l15 = lane & 15, l4 = lane >> 4;
        f32x4 acc[4];
#pragma unroll
        for (int mt = 0; mt < 4; ++mt)
#pragma unroll
            for (int j = 0; j < 4; ++j) acc[mt][j] = 0.f;
#pragma unroll
        for (int kt = 0; kt < 8; ++kt) {
            h16x8 b = *(const h16x8*)&A3t[(wave * 16 + l15) * 256 + kt * 32 + l4 * 8];
#pragma unroll
            for (int mt = 0; mt < 4; ++mt) {
                h16x8 a = *(const h16x8*)&S[(mt * 16 + l15) * LDS_S + kt * 32 + l4 * 8];
                acc[mt] = __builtin_amdgcn_mfma_f32_16x16x32_f16(a, b, acc[mt], 0, 0, 0);
            }
        }
        const int col = wave * 16 + l15;
        const float bv = c3[col];
#pragma unroll
        for (int mt = 0; mt < 4; ++mt)
#pragma unroll
            for (int r = 0; r < 4; ++r) {
                int row = row0 + mt * 16 + l4 * 4 + r;
                out[(size_t)row * 64 + col] = acc[mt][r] + bv;
            }
    }
}

// ---------------- host launch ----------------
extern "C" void kernel_launch(void* const* d_in, const int* in_sizes, int n_in,
                              void* d_out, int out_size, void* d_ws, size_t ws_size,
                              hipStream_t stream) {
    const float* x     = (const float*)d_in[0];
    const int*   aisle = (const int*)d_in[1];
    const int*   batch = (const int*)d_in[2];
    const float* W1 = (const float*)d_in[3];  const float* b1 = (const float*)d_in[4];
    const float* W2 = (const float*)d_in[5];  const float* b2 = (const float*)d_in[6];
    const float* W3 = (const float*)d_in[7];  const float* b3 = (const float*)d_in[8];
    const float* A1 = (const float*)d_in[9];  const float* c1 = (const float*)d_in[10];
    const float* A2 = (const float*)d_in[11]; const float* c2 = (const float*)d_in[12];
    const float* A3 = (const float*)d_in[13]; const float* c3 = (const float*)d_in[14];
    float* out = (float*)d_out;

    char* w = (char*)d_ws;
    size_t off = 0;
    h16*   hbuf   = (h16*)(w + off);   off += (size_t)N_ROWS * 128 * sizeof(h16);   // 64 MB
    float* sums   = (float*)(w + off); size_t sums_off = off; off += NSEG * 128 * sizeof(float);
    float* counts = (float*)(w + off); off += NSEG * sizeof(float);
    size_t zero_bytes = off - sums_off;
    h16*   means  = (h16*)(w + off);   off += NSEG * 128 * sizeof(h16);
    h16*   W1t    = (h16*)(w + off);   off += 16384 * sizeof(h16);
    h16*   W2t    = (h16*)(w + off);   off += 65536 * sizeof(h16);
    h16*   W3t    = (h16*)(w + off);   off += 32768 * sizeof(h16);
    h16*   A1t    = (h16*)(w + off);   off += 65536 * sizeof(h16);
    h16*   A2t    = (h16*)(w + off);   off += 65536 * sizeof(h16);
    h16*   A3t    = (h16*)(w + off);   off += 16384 * sizeof(h16);
    int*   maxA   = (int*)(w + off);   off += 256;

    hipMemsetAsync(w + sums_off, 0, zero_bytes, stream);
    hipMemsetAsync(maxA, 0, sizeof(int), stream);

    k_max<<<256, 256, 0, stream>>>(aisle, maxA);
    k_prep_weights<<<1024, 256, 0, stream>>>(W1, W2, W3, A1, A2, A3, W1t, W2t, W3t, A1t, A2t, A3t);
    k1<<<N_ROWS / 64, 256, 0, stream>>>(x, W1t, b1, W2t, b2, W3t, b3, hbuf);
    k_scatter<<<N_ROWS / CHUNK, 256, 0, stream>>>(hbuf, aisle, batch, sums, counts, maxA);
    k_means<<<512, 256, 0, stream>>>(sums, counts, means);
    k3<<<N_ROWS / 64, 256, 0, stream>>>(hbuf, aisle, batch, means, A1t, c1, A2t, c2, A3t, c3,
                                        out, maxA);
}

// Round 3
// 619.727 us; speedup vs baseline: 3.5237x; 1.0305x over previous
//
#include <hip/hip_runtime.h>
#include <hip/hip_bf16.h>

#define N_ROWS 262144
#define IN_DIM 64
#define HID 256
#define EMB 128
#define OUT_DIM 64
#define NSEG 1024
#define LDS_S 264   // 256 + 8 halves pad
#define CHUNK 512   // rows per k_scatter block

typedef _Float16 h16;
typedef _Float16 h16x8 __attribute__((ext_vector_type(8)));
typedef _Float16 h16x4 __attribute__((ext_vector_type(4)));
typedef float f32x4 __attribute__((ext_vector_type(4)));

// ---------------- prep kernels ----------------

__global__ void k_max(const int* __restrict__ aisle, int* __restrict__ maxA) {
    int v = 0;
    for (int i = blockIdx.x * blockDim.x + threadIdx.x; i < N_ROWS; i += gridDim.x * blockDim.x)
        v = max(v, aisle[i]);
#pragma unroll
    for (int off = 32; off > 0; off >>= 1) v = max(v, __shfl_down(v, off));
    __shared__ int red[4];
    if ((threadIdx.x & 63) == 0) red[threadIdx.x >> 6] = v;
    __syncthreads();
    if (threadIdx.x == 0) {
        int m = red[0];
        for (int i = 1; i < 4; ++i) m = max(m, red[i]);
        atomicMax(maxA, m);
    }
}

__global__ void k_prep_weights(const float* __restrict__ W1, const float* __restrict__ W2,
                               const float* __restrict__ W3, const float* __restrict__ A1f,
                               const float* __restrict__ A2f, const float* __restrict__ A3f,
                               h16* __restrict__ W1t, h16* __restrict__ W2t, h16* __restrict__ W3t,
                               h16* __restrict__ A1t, h16* __restrict__ A2t, h16* __restrict__ A3t) {
    int idx = blockIdx.x * 256 + threadIdx.x;      // total 262144 threads
    if (idx < 16384)       { int o = idx;          int n = o >> 6, k = o & 63;  W1t[o] = (h16)W1[k * 256 + n]; }
    else if (idx < 81920)  { int o = idx - 16384;  int n = o >> 8, k = o & 255; W2t[o] = (h16)W2[k * 256 + n]; }
    else if (idx < 114688) { int o = idx - 81920;  int n = o >> 8, k = o & 255; W3t[o] = (h16)W3[k * 128 + n]; }
    else if (idx < 180224) { int o = idx - 114688; int n = o >> 8, k = o & 255; A1t[o] = (h16)A1f[k * 256 + n]; }
    else if (idx < 245760) { int o = idx - 180224; int n = o >> 8, k = o & 255; A2t[o] = (h16)A2f[k * 256 + n]; }
    else                   { int o = idx - 245760; int n = o >> 8, k = o & 255; A3t[o] = (h16)A3f[k * 64  + n]; }
}

__global__ void k_means(const float* __restrict__ sums, const float* __restrict__ counts,
                        h16* __restrict__ means) {
    int i = blockIdx.x * 256 + threadIdx.x;        // 131072 total
    int s = i >> 7;
    float c = counts[s];
    means[i] = (h16)(sums[i] / fmaxf(c, 1.0f));
}

// ---------------- fused MLP layer (in-place LDS, swapped-operand MFMA) ----------------
// S: [64 rows][K cols] fp16 acts, stride LDS_S. Computes lrelu?(S @ Wt^T + bias)
// into S[64][NOUT]. Wt is [NOUT][K] fp16.
// mfma(w_frag, a_frag, acc): D[n][m] with D-layout row=(lane>>4)*4+r -> weight col n,
// col=lane&15 -> act row m. Lane's 4 regs = 4 consecutive output cols -> b64 stores.
// B-frags pipelined one kt ahead (bc/bn) to hide L2 latency.
template <int K, int NOUT, bool ACT>
__device__ __forceinline__ void mlp_layer(const h16* __restrict__ Wt,
                                          const float* __restrict__ bias,
                                          h16* S, int lane, int wave) {
    constexpr int NW = NOUT / 4;   // cols per wave
    constexpr int NT = NW / 16;    // n-tiles per wave
    constexpr int KT = K / 32;     // k-steps
    const int l15 = lane & 15, l4 = lane >> 4;
    f32x4 acc[4][NT];
#pragma unroll
    for (int mt = 0; mt < 4; ++mt)
#pragma unroll
        for (int nt = 0; nt < NT; ++nt)
#pragma unroll
            for (int j = 0; j < 4; ++j) acc[mt][nt][j] = 0.f;

    const h16* wb[NT];
    f32x4 bias4[NT];
#pragma unroll
    for (int nt = 0; nt < NT; ++nt) {
        wb[nt] = Wt + (size_t)(wave * NW + nt * 16 + l15) * K + l4 * 8;
        bias4[nt] = *(const f32x4*)&bias[wave * NW + nt * 16 + l4 * 4];
    }

    h16x8 bc[NT], bn[NT];
#pragma unroll
    for (int nt = 0; nt < NT; ++nt) bn[nt] = *(const h16x8*)wb[nt];

#pragma unroll
    for (int kt = 0; kt < KT; ++kt) {
#pragma unroll
        for (int nt = 0; nt < NT; ++nt) bc[nt] = bn[nt];
        if (kt + 1 < KT) {
#pragma unroll
            for (int nt = 0; nt < NT; ++nt) bn[nt] = *(const h16x8*)(wb[nt] + (kt + 1) * 32);
        }
#pragma unroll
        for (int mt = 0; mt < 4; ++mt) {
            h16x8 a = *(const h16x8*)&S[(mt * 16 + l15) * LDS_S + kt * 32 + l4 * 8];
#pragma unroll
            for (int nt = 0; nt < NT; ++nt)
                acc[mt][nt] = __builtin_amdgcn_mfma_f32_16x16x32_f16(bc[nt], a, acc[mt][nt], 0, 0, 0);
        }
    }
    __syncthreads();   // all reads of S done before in-place overwrite
#pragma unroll
    for (int nt = 0; nt < NT; ++nt) {
        const int cb = wave * NW + nt * 16 + l4 * 4;
#pragma unroll
        for (int mt = 0; mt < 4; ++mt) {
            f32x4 v = acc[mt][nt] + bias4[nt];
            if (ACT) {
#pragma unroll
                for (int j = 0; j < 4; ++j) v[j] = (v[j] > 0.f) ? v[j] : 0.01f * v[j];
            }
            h16x4 hv;
#pragma unroll
            for (int j = 0; j < 4; ++j) hv[j] = (h16)v[j];
            *(h16x4*)&S[(mt * 16 + l15) * LDS_S + cb] = hv;
        }
    }
    __syncthreads();   // new acts visible
}

// ---------------- phase 1: x -> h ----------------
__global__ __launch_bounds__(256) void k1(const float* __restrict__ x,
                                          const h16* __restrict__ W1t, const float* __restrict__ b1,
                                          const h16* __restrict__ W2t, const float* __restrict__ b2,
                                          const h16* __restrict__ W3t, const float* __restrict__ b3,
                                          h16* __restrict__ hbuf) {
    __shared__ __align__(16) h16 S[64 * LDS_S];
    const int tid = threadIdx.x, lane = tid & 63, wave = tid >> 6;
    const int row0 = blockIdx.x * 64;

    for (int i = tid; i < 1024; i += 256) {
        int r = i >> 4, c4 = (i & 15) * 4;
        f32x4 v = *(const f32x4*)&x[(size_t)(row0 + r) * 64 + c4];
        h16* dst = &S[r * LDS_S + c4];
        dst[0] = (h16)v[0]; dst[1] = (h16)v[1]; dst[2] = (h16)v[2]; dst[3] = (h16)v[3];
    }
    __syncthreads();

    mlp_layer<64, 256, true>(W1t, b1, S, lane, wave);
    mlp_layer<256, 256, true>(W2t, b2, S, lane, wave);
    mlp_layer<256, 128, false>(W3t, b3, S, lane, wave);

    for (int i = tid; i < 1024; i += 256) {
        int r = i >> 4, c8 = (i & 15) * 8;
        *(h16x8*)&hbuf[(size_t)(row0 + r) * 128 + c8] = *(const h16x8*)&S[r * LDS_S + c8];
    }
}

// ---------------- phase 2: hierarchical segment-sum scatter ----------------
__global__ __launch_bounds__(256) void k_scatter(const h16* __restrict__ hbuf,
                                                 const int* __restrict__ aisle,
                                                 const int* __restrict__ batch,
                                                 float* __restrict__ sums,
                                                 float* __restrict__ counts,
                                                 const int* __restrict__ maxA) {
    __shared__ float acc[64][132];
    __shared__ float cnt[64];
    const int tid = threadIdx.x;
    const int row0 = blockIdx.x * CHUNK;
    const int mult = *maxA + 1;

    for (int i = tid; i < 64 * 132; i += 256) ((float*)acc)[i] = 0.f;
    if (tid < 64) cnt[tid] = 0.f;
    __syncthreads();

    const int bLo = batch[row0], bHi = batch[row0 + CHUNK - 1];
    const int w = tid >> 4;           // 16 row-walkers
    const int c8 = (tid & 15) * 8;    // 8 cols per thread

    for (int bv = bLo; bv <= bHi; ++bv) {
        for (int r = w; r < CHUNK; r += 16) {
            const int g = row0 + r;
            if (batch[g] != bv) continue;
            const int a = aisle[g];
            const h16x8 hv = *(const h16x8*)&hbuf[(size_t)g * 128 + c8];
#pragma unroll
            for (int j = 0; j < 8; ++j) atomicAdd(&acc[a][c8 + j], (float)hv[j]);
            if (c8 == 0) atomicAdd(&cnt[a], 1.0f);
        }
        __syncthreads();
        for (int i = tid; i < 64 * 128; i += 256) {
            const int a = i >> 7, c = i & 127;
            const float v = acc[a][c];
            if (v != 0.f) {
                atomicAdd(&sums[(size_t)(a + bv * mult) * 128 + c], v);
                acc[a][c] = 0.f;
            }
        }
        if (tid < 64 && cnt[tid] != 0.f) {
            atomicAdd(&counts[tid + bv * mult], cnt[tid]);
            cnt[tid] = 0.f;
        }
        __syncthreads();
    }
}

// ---------------- phase 3: concat(h, mean) -> out ----------------
__global__ __launch_bounds__(256) void k3(const h16* __restrict__ hbuf,
                                          const int* __restrict__ aisle,
                                          const int* __restrict__ batch,
                                          const h16* __restrict__ means,
                                          const h16* __restrict__ A1t, const float* __restrict__ c1,
                                          const h16* __restrict__ A2t, const float* __restrict__ c2,
                                          const h16* __restrict__ A3t, const float* __restrict__ c3,
                                          float* __restrict__ out, const int* __restrict__ maxA) {
    __shared__ __align__(16) h16 S[64 * LDS_S];
    const int tid = threadIdx.x, lane = tid & 63, wave = tid >> 6;
    const int row0 = blockIdx.x * 64;
    const int mult = *maxA + 1;

    for (int i = tid; i < 1024; i += 256) {
        int r = i >> 4, c8 = (i & 15) * 8;
        *(h16x8*)&S[r * LDS_S + c8] = *(const h16x8*)&hbuf[(size_t)(row0 + r) * 128 + c8];
    }
    {
        const int r = tid >> 2, p = tid & 3;
        const int g = row0 + r;
        const int id = aisle[g] + batch[g] * mult;
        const h16x8* src = (const h16x8*)&means[id * 128 + p * 32];
        h16x8* dst = (h16x8*)&S[r * LDS_S + 128 + p * 32];
        dst[0] = src[0]; dst[1] = src[1]; dst[2] = src[2]; dst[3] = src[3];
    }
    __syncthreads();

    mlp_layer<256, 256, true>(A1t, c1, S, lane, wave);
    mlp_layer<256, 256, true>(A2t, c2, S, lane, wave);

    // final layer: K=256 -> 64 cols, swapped operands, fp32 f32x4 stores
    {
        const int l15 = lane & 15, l4 = lane >> 4;
        f32x4 acc4[4];
#pragma unroll
        for (int mt = 0; mt < 4; ++mt)
#pragma unroll
            for (int j = 0; j < 4; ++j) acc4[mt][j] = 0.f;
        const h16* wb = A3t + (size_t)(wave * 16 + l15) * 256 + l4 * 8;
        h16x8 bn = *(const h16x8*)wb, bc;
#pragma unroll
        for (int kt = 0; kt < 8; ++kt) {
            bc = bn;
            if (kt < 7) bn = *(const h16x8*)(wb + (kt + 1) * 32);
#pragma unroll
            for (int mt = 0; mt < 4; ++mt) {
                h16x8 a = *(const h16x8*)&S[(mt * 16 + l15) * LDS_S + kt * 32 + l4 * 8];
                acc4[mt] = __builtin_amdgcn_mfma_f32_16x16x32_f16(bc, a, acc4[mt], 0, 0, 0);
            }
        }
        const f32x4 bias4 = *(const f32x4*)&c3[wave * 16 + l4 * 4];
#pragma unroll
        for (int mt = 0; mt < 4; ++mt) {
            f32x4 v = acc4[mt] + bias4;
            *(f32x4*)&out[(size_t)(row0 + mt * 16 + l15) * 64 + wave * 16 + l4 * 4] = v;
        }
    }
}

// ---------------- host launch ----------------
extern "C" void kernel_launch(void* const* d_in, const int* in_sizes, int n_in,
                              void* d_out, int out_size, void* d_ws, size_t ws_size,
                              hipStream_t stream) {
    const float* x     = (const float*)d_in[0];
    const int*   aisle = (const int*)d_in[1];
    const int*   batch = (const int*)d_in[2];
    const float* W1 = (const float*)d_in[3];  const float* b1 = (const float*)d_in[4];
    const float* W2 = (const float*)d_in[5];  const float* b2 = (const float*)d_in[6];
    const float* W3 = (const float*)d_in[7];  const float* b3 = (const float*)d_in[8];
    const float* A1 = (const float*)d_in[9];  const float* c1 = (const float*)d_in[10];
    const float* A2 = (const float*)d_in[11]; const float* c2 = (const float*)d_in[12];
    const float* A3 = (const float*)d_in[13]; const float* c3 = (const float*)d_in[14];
    float* out = (float*)d_out;

    char* w = (char*)d_ws;
    size_t off = 0;
    h16*   hbuf   = (h16*)(w + off);   off += (size_t)N_ROWS * 128 * sizeof(h16);   // 64 MB
    float* sums   = (float*)(w + off); size_t sums_off = off; off += NSEG * 128 * sizeof(float);
    float* counts = (float*)(w + off); off += NSEG * sizeof(float);
    size_t zero_bytes = off - sums_off;
    h16*   means  = (h16*)(w + off);   off += NSEG * 128 * sizeof(h16);
    h16*   W1t    = (h16*)(w + off);   off += 16384 * sizeof(h16);
    h16*   W2t    = (h16*)(w + off);   off += 65536 * sizeof(h16);
    h16*   W3t    = (h16*)(w + off);   off += 32768 * sizeof(h16);
    h16*   A1t    = (h16*)(w + off);   off += 65536 * sizeof(h16);
    h16*   A2t    = (h16*)(w + off);   off += 65536 * sizeof(h16);
    h16*   A3t    = (h16*)(w + off);   off += 16384 * sizeof(h16);
    int*   maxA   = (int*)(w + off);   off += 256;

    hipMemsetAsync(w + sums_off, 0, zero_bytes, stream);
    hipMemsetAsync(maxA, 0, sizeof(int), stream);

    k_max<<<256, 256, 0, stream>>>(aisle, maxA);
    k_prep_weights<<<1024, 256, 0, stream>>>(W1, W2, W3, A1, A2, A3, W1t, W2t, W3t, A1t, A2t, A3t);
    k1<<<N_ROWS / 64, 256, 0, stream>>>(x, W1t, b1, W2t, b2, W3t, b3, hbuf);
    k_scatter<<<N_ROWS / CHUNK, 256, 0, stream>>>(hbuf, aisle, batch, sums, counts, maxA);
    k_means<<<512, 256, 0, stream>>>(sums, counts, means);
    k3<<<N_ROWS / 64, 256, 0, stream>>>(hbuf, aisle, batch, means, A1t, c1, A2t, c2, A3t, c3,
                                        out, maxA);
}